// Round 2
// baseline (429.657 us; speedup 1.0000x reference)
//
#include <hip/hip_runtime.h>
#include <cstdint>
#include <cstddef>

// Problem: a[B=4,S=2048,K=4096] int8, w[K=4096,N=4096] int8,
// a_s[8192] f32 per-token scale, w_s[4096] f32 per-col scale.
// out[m][n] = fp16( (int32 dot) * a_s[m] * w_s[n] ), stored as f32 in d_out.
//
// HARNESS NOTE: integer inputs arrive as *int32* buffers (one int32 per
// reference int8 element). Pre-pass kernels narrow them to packed int8 in
// d_ws before the MFMA GEMM.

#define M_DIM 8192
#define N_DIM 4096
#define K_DIM 4096

typedef int v4i __attribute__((ext_vector_type(4)));

// ---------------------------------------------------------------------------
// Kernel 0: narrow a int32[M*K] -> int8[M*K], same layout.
// Each thread: 16 int32 (4x int4 loads, 64 B) -> 16 bytes (1x uint4 store).
// ---------------------------------------------------------------------------
__global__ void __launch_bounds__(256) pack_a_kernel(
    const int* __restrict__ a, uint8_t* __restrict__ pa)
{
    const size_t idx = (size_t)blockIdx.x * 256 + threadIdx.x;
    const int4* src = (const int4*)a + idx * 4;
    int4 x0 = src[0], x1 = src[1], x2 = src[2], x3 = src[3];
    uint32_t o0 = (uint32_t)(x0.x & 0xff) | ((uint32_t)(x0.y & 0xff) << 8) |
                  ((uint32_t)(x0.z & 0xff) << 16) | ((uint32_t)(x0.w & 0xff) << 24);
    uint32_t o1 = (uint32_t)(x1.x & 0xff) | ((uint32_t)(x1.y & 0xff) << 8) |
                  ((uint32_t)(x1.z & 0xff) << 16) | ((uint32_t)(x1.w & 0xff) << 24);
    uint32_t o2 = (uint32_t)(x2.x & 0xff) | ((uint32_t)(x2.y & 0xff) << 8) |
                  ((uint32_t)(x2.z & 0xff) << 16) | ((uint32_t)(x2.w & 0xff) << 24);
    uint32_t o3 = (uint32_t)(x3.x & 0xff) | ((uint32_t)(x3.y & 0xff) << 8) |
                  ((uint32_t)(x3.z & 0xff) << 16) | ((uint32_t)(x3.w & 0xff) << 24);
    ((uint4*)pa)[idx] = make_uint4(o0, o1, o2, o3);
}

// ---------------------------------------------------------------------------
// Kernel 1: w int32[K][N] -> wt int8[N][K] (narrow + transpose), 64x64 tiles.
// ---------------------------------------------------------------------------
__global__ void __launch_bounds__(256) pack_transpose_w_kernel(
    const int* __restrict__ w, uint8_t* __restrict__ wt)
{
    __shared__ int lds[64][65];        // [k][n] int32 values, +1 pad
    const int t  = threadIdx.x;
    const int n0 = blockIdx.x * 64;
    const int k0 = blockIdx.y * 64;

    // Load 64x64 int32 tile, coalesced int4 loads.
#pragma unroll
    for (int i = 0; i < 4; ++i) {
        int v   = t + 256 * i;         // 0..1023 int4-groups
        int row = v >> 4;              // k within tile
        int cq  = v & 15;              // int4 group within row
        int4 x = *(const int4*)(w + (size_t)(k0 + row) * N_DIM + n0 + cq * 4);
        lds[row][cq * 4 + 0] = x.x;
        lds[row][cq * 4 + 1] = x.y;
        lds[row][cq * 4 + 2] = x.z;
        lds[row][cq * 4 + 3] = x.w;
    }
    __syncthreads();

    // Thread t emits 16 bytes of output row n_local: wt[n0+n_local][k0+c*16 ..]
    const int n_local = t >> 2;        // 0..63
    const int c       = t & 3;         // 16-byte k-chunk
    uint32_t o[4];
#pragma unroll
    for (int j = 0; j < 4; ++j) {
        uint32_t r = 0;
#pragma unroll
        for (int b = 0; b < 4; ++b)
            r |= (uint32_t)(lds[c * 16 + j * 4 + b][n_local] & 0xff) << (8 * b);
        o[j] = r;
    }
    *(uint4*)(wt + (size_t)(n0 + n_local) * K_DIM + k0 + c * 16) =
        make_uint4(o[0], o[1], o[2], o[3]);
}

// ---------------------------------------------------------------------------
// Kernel 2: int8 GEMM, m97-style structure.
// Block tile 128(M) x 128(N), BK = 128 bytes. 256 threads = 4 waves in 2x2;
// each wave computes 64x64 via 4x4 grid of mfma_i32_16x16x64_i8.
// LDS: sA[128 rows][128 k-bytes], sB[128 n-rows][128 k-bytes], both with the
// 16B-chunk XOR swizzle (chunk ^= row&7) applied at *global-address* time so
// the global_load_lds contiguous-dest constraint is preserved.
// ---------------------------------------------------------------------------
__device__ __forceinline__ void async_copy16(const void* gptr, void* lptr)
{
    __builtin_amdgcn_global_load_lds(
        (const __attribute__((address_space(1))) uint32_t*)gptr,
        (__attribute__((address_space(3))) uint32_t*)lptr,
        16, 0, 0);
}

__global__ void __launch_bounds__(256) int8_gemm_kernel(
    const uint8_t* __restrict__ A,    // [M][K] int8 bytes (packed)
    const uint8_t* __restrict__ Wt,   // [N][K] int8 bytes (pre-transposed)
    const float*   __restrict__ a_s,  // [M]
    const float*   __restrict__ w_s,  // [N]
    float*         __restrict__ out)  // [M][N] f32 (fp16-rounded)
{
    __shared__ __align__(16) uint8_t sA[128 * 128];
    __shared__ __align__(16) uint8_t sB[128 * 128];

    const int tid   = threadIdx.x;
    const int wave  = tid >> 6;
    const int lane  = tid & 63;
    const int waveM = wave >> 1;      // 0..1
    const int waveN = wave & 1;       // 0..1

    const int bm = blockIdx.x & 63;   // 64 m-blocks (fast)
    const int bn = blockIdx.x >> 6;   // 32 n-blocks
    const int m0 = bm * 128;
    const int n0 = bn * 128;

    v4i acc[4][4];
#pragma unroll
    for (int i = 0; i < 4; ++i)
#pragma unroll
        for (int j = 0; j < 4; ++j)
            acc[i][j] = (v4i){0, 0, 0, 0};

    // Staging geometry: 16 regions of 1KB each (8 rows x 128B). Region
    // = wave*4 + s. Lane covers row (lane>>3) of the region, 16B chunk (lane&7).
    const int sr = lane >> 3;   // row within region
    const int sc = lane & 7;    // chunk within row

    const int quad = lane >> 4; // 0..3
    const int rowA = lane & 15; // m/n within 16-tile

    for (int kt = 0; kt < K_DIM / 128; ++kt) {
        const int k0 = kt * 128;
#pragma unroll
        for (int s = 0; s < 4; ++s) {
            const int region = wave * 4 + s;        // wave-uniform
            const int r      = region * 8 + sr;     // tile row 0..127
            const int g      = sc ^ (r & 7);        // swizzled global chunk
            async_copy16(A  + (size_t)(m0 + r) * K_DIM + k0 + g * 16,
                         &sA[region * 1024]);
            async_copy16(Wt + (size_t)(n0 + r) * K_DIM + k0 + g * 16,
                         &sB[region * 1024]);
        }
        __syncthreads();   // drains vmcnt(0): staged data visible

#pragma unroll
        for (int kk = 0; kk < 2; ++kk) {
            v4i af[4], bf[4];
            const int gc = kk * 4 + quad;  // global 16B k-chunk this lane needs
#pragma unroll
            for (int t = 0; t < 4; ++t) {
                const int mr = waveM * 64 + t * 16 + rowA;
                af[t] = *(const v4i*)(sA + mr * 128 + ((gc ^ (mr & 7)) << 4));
                const int nr = waveN * 64 + t * 16 + rowA;
                bf[t] = *(const v4i*)(sB + nr * 128 + ((gc ^ (nr & 7)) << 4));
            }
#pragma unroll
            for (int mt = 0; mt < 4; ++mt)
#pragma unroll
                for (int nt = 0; nt < 4; ++nt)
                    acc[mt][nt] = __builtin_amdgcn_mfma_i32_16x16x64_i8(
                        af[mt], bf[nt], acc[mt][nt], 0, 0, 0);
        }
        __syncthreads();   // compute done before next overwrite
    }

    // Epilogue. C/D layout: col = lane&15, row = quad*4 + reg.
    const int col = lane & 15;
    float asv[4][4];
#pragma unroll
    for (int mt = 0; mt < 4; ++mt)
#pragma unroll
        for (int r = 0; r < 4; ++r)
            asv[mt][r] = a_s[m0 + waveM * 64 + mt * 16 + quad * 4 + r];

#pragma unroll
    for (int nt = 0; nt < 4; ++nt) {
        const int n   = n0 + waveN * 64 + nt * 16 + col;
        const float wsv = w_s[n];
#pragma unroll
        for (int mt = 0; mt < 4; ++mt) {
            const int mbase = m0 + waveM * 64 + mt * 16 + quad * 4;
#pragma unroll
            for (int r = 0; r < 4; ++r) {
                float v = (float)acc[mt][nt][r] * asv[mt][r] * wsv;
                // match reference's fp16 cast
                v = (float)(_Float16)v;
                out[(size_t)(mbase + r) * N_DIM + n] = v;
            }
        }
    }
}

// ---------------------------------------------------------------------------
extern "C" void kernel_launch(void* const* d_in, const int* in_sizes, int n_in,
                              void* d_out, int out_size, void* d_ws, size_t ws_size,
                              hipStream_t stream)
{
    const int*   a   = (const int*)  d_in[0];  // int32-widened int8 [8192][4096]
    const float* a_s = (const float*)d_in[1];  // [8192]
    const int*   w   = (const int*)  d_in[2];  // int32-widened int8 [4096][4096]
    const float* w_s = (const float*)d_in[3];  // [4096]
    float*       out = (float*)d_out;

    uint8_t* wt = (uint8_t*)d_ws;                          // 16 MiB
    uint8_t* pa = (uint8_t*)d_ws + (size_t)N_DIM * K_DIM;  // 32 MiB

    // Narrow A: M*K/16 threads, 256/block.
    pack_a_kernel<<<(M_DIM * (K_DIM / 16)) / 256, 256, 0, stream>>>(a, pa);

    // Narrow + transpose W.
    dim3 tgrid(N_DIM / 64, K_DIM / 64);
    pack_transpose_w_kernel<<<tgrid, 256, 0, stream>>>(w, wt);

    int8_gemm_kernel<<<(M_DIM / 128) * (N_DIM / 128), 256, 0, stream>>>(
        pa, wt, a_s, w_s, out);
}

// Round 3
// 429.582 us; speedup vs baseline: 1.0002x; 1.0002x over previous
//
#include <hip/hip_runtime.h>
#include <cstdint>
#include <cstddef>

// Problem: a[B=4,S=2048,K=4096] int8, w[K=4096,N=4096] int8,
// a_s[8192] f32 per-token scale, w_s[4096] f32 per-col scale.
// out[m][n] = fp16( (int32 dot) * a_s[m] * w_s[n] ), stored as f32 in d_out.
//
// HARNESS NOTE: integer inputs arrive as *int32* buffers (one int32 per
// reference int8 element). A fused pre-pass narrows them to packed int8 in
// d_ws (A: same layout; W: transposed to [N][K]) before the MFMA GEMM.

#define M_DIM 8192
#define N_DIM 4096
#define K_DIM 4096

// pack-A portion: one thread per 4 int32 -> 1 uint32. M*K/4 = 8M threads.
#define PACKA_BLOCKS ((M_DIM * K_DIM / 4) / 256)   // 32768
// transpose portion: 64x64 tiles -> (4096/64)*(4096/64) = 4096 blocks.
#define TRANS_BLOCKS ((N_DIM / 64) * (K_DIM / 64)) // 4096

typedef int v4i __attribute__((ext_vector_type(4)));

__device__ __forceinline__ uint32_t pack4(int x, int y, int z, int w)
{
    return (uint32_t)(x & 0xff) | ((uint32_t)(y & 0xff) << 8) |
           ((uint32_t)(z & 0xff) << 16) | ((uint32_t)(w & 0xff) << 24);
}

// ---------------------------------------------------------------------------
// Fused pre-pass: blocks [0, PACKA_BLOCKS) narrow A (layout-preserving,
// fully coalesced: lane i loads int4 at +16B stride, stores uint32 at +4B
// stride). Blocks [PACKA_BLOCKS, ...) narrow + transpose W via 64x64 LDS
// tiles. One kernel so the two independent passes run concurrently instead
// of serializing on the stream.
// ---------------------------------------------------------------------------
__global__ void __launch_bounds__(256) prepare_kernel(
    const int* __restrict__ a, const int* __restrict__ w,
    uint8_t* __restrict__ pa, uint8_t* __restrict__ wt)
{
    __shared__ int lds[64][65];        // used by transpose branch only

    if (blockIdx.x < PACKA_BLOCKS) {
        const size_t idx = (size_t)blockIdx.x * 256 + threadIdx.x;
        int4 x = ((const int4*)a)[idx];
        ((uint32_t*)pa)[idx] = pack4(x.x, x.y, x.z, x.w);
        return;
    }

    const int tile = blockIdx.x - PACKA_BLOCKS;
    const int t  = threadIdx.x;
    const int n0 = (tile & 63) * 64;
    const int k0 = (tile >> 6) * 64;

    // Load 64x64 int32 tile, coalesced int4 loads.
#pragma unroll
    for (int i = 0; i < 4; ++i) {
        int v   = t + 256 * i;         // 0..1023 int4-groups
        int row = v >> 4;              // k within tile
        int cq  = v & 15;              // int4 group within row
        int4 x = *(const int4*)(w + (size_t)(k0 + row) * N_DIM + n0 + cq * 4);
        lds[row][cq * 4 + 0] = x.x;
        lds[row][cq * 4 + 1] = x.y;
        lds[row][cq * 4 + 2] = x.z;
        lds[row][cq * 4 + 3] = x.w;
    }
    __syncthreads();

    // Thread t emits 16 bytes of output row n_local: wt[n0+n_local][k0+c*16 ..]
    const int n_local = t >> 2;        // 0..63
    const int c       = t & 3;         // 16-byte k-chunk
    uint32_t o[4];
#pragma unroll
    for (int j = 0; j < 4; ++j)
        o[j] = pack4(lds[c * 16 + j * 4 + 0][n_local],
                     lds[c * 16 + j * 4 + 1][n_local],
                     lds[c * 16 + j * 4 + 2][n_local],
                     lds[c * 16 + j * 4 + 3][n_local]);
    *(uint4*)(wt + (size_t)(n0 + n_local) * K_DIM + k0 + c * 16) =
        make_uint4(o[0], o[1], o[2], o[3]);
}

// ---------------------------------------------------------------------------
// int8 GEMM, m97-style structure.
// Block tile 128(M) x 128(N), BK = 128 bytes. 256 threads = 4 waves in 2x2;
// each wave computes 64x64 via 4x4 grid of mfma_i32_16x16x64_i8.
// LDS: sA[128 rows][128 k-bytes], sB[128 n-rows][128 k-bytes], both with the
// 16B-chunk XOR swizzle (chunk ^= row&7) applied at *global-address* time so
// the global_load_lds contiguous-dest constraint is preserved.
// ---------------------------------------------------------------------------
__device__ __forceinline__ void async_copy16(const void* gptr, void* lptr)
{
    __builtin_amdgcn_global_load_lds(
        (const __attribute__((address_space(1))) uint32_t*)gptr,
        (__attribute__((address_space(3))) uint32_t*)lptr,
        16, 0, 0);
}

__global__ void __launch_bounds__(256) int8_gemm_kernel(
    const uint8_t* __restrict__ A,    // [M][K] int8 bytes (packed)
    const uint8_t* __restrict__ Wt,   // [N][K] int8 bytes (pre-transposed)
    const float*   __restrict__ a_s,  // [M]
    const float*   __restrict__ w_s,  // [N]
    float*         __restrict__ out)  // [M][N] f32 (fp16-rounded)
{
    __shared__ __align__(16) uint8_t sA[128 * 128];
    __shared__ __align__(16) uint8_t sB[128 * 128];

    const int tid   = threadIdx.x;
    const int wave  = tid >> 6;
    const int lane  = tid & 63;
    const int waveM = wave >> 1;      // 0..1
    const int waveN = wave & 1;       // 0..1

    const int bm = blockIdx.x & 63;   // 64 m-blocks (fast)
    const int bn = blockIdx.x >> 6;   // 32 n-blocks
    const int m0 = bm * 128;
    const int n0 = bn * 128;

    v4i acc[4][4];
#pragma unroll
    for (int i = 0; i < 4; ++i)
#pragma unroll
        for (int j = 0; j < 4; ++j)
            acc[i][j] = (v4i){0, 0, 0, 0};

    // Staging geometry: 16 regions of 1KB each (8 rows x 128B). Region
    // = wave*4 + s. Lane covers row (lane>>3) of the region, 16B chunk (lane&7).
    const int sr = lane >> 3;   // row within region
    const int sc = lane & 7;    // chunk within row

    const int quad = lane >> 4; // 0..3
    const int rowA = lane & 15; // m/n within 16-tile

    for (int kt = 0; kt < K_DIM / 128; ++kt) {
        const int k0 = kt * 128;
#pragma unroll
        for (int s = 0; s < 4; ++s) {
            const int region = wave * 4 + s;        // wave-uniform
            const int r      = region * 8 + sr;     // tile row 0..127
            const int g      = sc ^ (r & 7);        // swizzled global chunk
            async_copy16(A  + (size_t)(m0 + r) * K_DIM + k0 + g * 16,
                         &sA[region * 1024]);
            async_copy16(Wt + (size_t)(n0 + r) * K_DIM + k0 + g * 16,
                         &sB[region * 1024]);
        }
        __syncthreads();   // drains vmcnt(0): staged data visible

#pragma unroll
        for (int kk = 0; kk < 2; ++kk) {
            v4i af[4], bf[4];
            const int gc = kk * 4 + quad;  // global 16B k-chunk this lane needs
#pragma unroll
            for (int t = 0; t < 4; ++t) {
                const int mr = waveM * 64 + t * 16 + rowA;
                af[t] = *(const v4i*)(sA + mr * 128 + ((gc ^ (mr & 7)) << 4));
                const int nr = waveN * 64 + t * 16 + rowA;
                bf[t] = *(const v4i*)(sB + nr * 128 + ((gc ^ (nr & 7)) << 4));
            }
#pragma unroll
            for (int mt = 0; mt < 4; ++mt)
#pragma unroll
                for (int nt = 0; nt < 4; ++nt)
                    acc[mt][nt] = __builtin_amdgcn_mfma_i32_16x16x64_i8(
                        af[mt], bf[nt], acc[mt][nt], 0, 0, 0);
        }
        __syncthreads();   // compute done before next overwrite
    }

    // Epilogue. C/D layout: col = lane&15, row = quad*4 + reg.
    const int col = lane & 15;
    float asv[4][4];
#pragma unroll
    for (int mt = 0; mt < 4; ++mt)
#pragma unroll
        for (int r = 0; r < 4; ++r)
            asv[mt][r] = a_s[m0 + waveM * 64 + mt * 16 + quad * 4 + r];

#pragma unroll
    for (int nt = 0; nt < 4; ++nt) {
        const int n   = n0 + waveN * 64 + nt * 16 + col;
        const float wsv = w_s[n];
#pragma unroll
        for (int mt = 0; mt < 4; ++mt) {
            const int mbase = m0 + waveM * 64 + mt * 16 + quad * 4;
#pragma unroll
            for (int r = 0; r < 4; ++r) {
                float v = (float)acc[mt][nt][r] * asv[mt][r] * wsv;
                // match reference's fp16 cast
                v = (float)(_Float16)v;
                out[(size_t)(mbase + r) * N_DIM + n] = v;
            }
        }
    }
}

// ---------------------------------------------------------------------------
extern "C" void kernel_launch(void* const* d_in, const int* in_sizes, int n_in,
                              void* d_out, int out_size, void* d_ws, size_t ws_size,
                              hipStream_t stream)
{
    const int*   a   = (const int*)  d_in[0];  // int32-widened int8 [8192][4096]
    const float* a_s = (const float*)d_in[1];  // [8192]
    const int*   w   = (const int*)  d_in[2];  // int32-widened int8 [4096][4096]
    const float* w_s = (const float*)d_in[3];  // [4096]
    float*       out = (float*)d_out;

    uint8_t* wt = (uint8_t*)d_ws;                          // 16 MiB
    uint8_t* pa = (uint8_t*)d_ws + (size_t)N_DIM * K_DIM;  // 32 MiB

    prepare_kernel<<<PACKA_BLOCKS + TRANS_BLOCKS, 256, 0, stream>>>(a, w, pa, wt);

    int8_gemm_kernel<<<(M_DIM / 128) * (N_DIM / 128), 256, 0, stream>>>(
        pa, wt, a_s, w_s, out);
}

// Round 4
// 416.316 us; speedup vs baseline: 1.0320x; 1.0319x over previous
//
#include <hip/hip_runtime.h>
#include <cstdint>
#include <cstddef>

// Problem: a[B=4,S=2048,K=4096] int8, w[K=4096,N=4096] int8,
// a_s[8192] f32 per-token scale, w_s[4096] f32 per-col scale.
// out[m][n] = fp16( (int32 dot) * a_s[m] * w_s[n] ), stored as f32 in d_out.
//
// HARNESS NOTE: integer inputs arrive as *int32* buffers (one int32 per
// reference int8 element). A fused pre-pass narrows them to packed int8 in
// d_ws (A: same layout; W: transposed to [N][K]) before the MFMA GEMM.

#define M_DIM 8192
#define N_DIM 4096
#define K_DIM 4096

// pack-A portion: one thread per 4 int32 -> 1 uint32. M*K/4 = 8M threads.
#define PACKA_BLOCKS ((M_DIM * K_DIM / 4) / 256)   // 32768
// transpose portion: 64x64 tiles -> (4096/64)*(4096/64) = 4096 blocks.
#define TRANS_BLOCKS ((N_DIM / 64) * (K_DIM / 64)) // 4096

typedef int v4i  __attribute__((ext_vector_type(4)));
typedef int v16i __attribute__((ext_vector_type(16)));

__device__ __forceinline__ uint32_t pack4(int x, int y, int z, int w)
{
    return (uint32_t)(x & 0xff) | ((uint32_t)(y & 0xff) << 8) |
           ((uint32_t)(z & 0xff) << 16) | ((uint32_t)(w & 0xff) << 24);
}

// ---------------------------------------------------------------------------
// Fused pre-pass: blocks [0, PACKA_BLOCKS) narrow A (layout-preserving,
// fully coalesced). Blocks [PACKA_BLOCKS, ...) narrow + transpose W via
// 64x64 LDS tiles.
// ---------------------------------------------------------------------------
__global__ void __launch_bounds__(256) prepare_kernel(
    const int* __restrict__ a, const int* __restrict__ w,
    uint8_t* __restrict__ pa, uint8_t* __restrict__ wt)
{
    __shared__ int lds[64][65];        // used by transpose branch only

    if (blockIdx.x < PACKA_BLOCKS) {
        const size_t idx = (size_t)blockIdx.x * 256 + threadIdx.x;
        int4 x = ((const int4*)a)[idx];
        ((uint32_t*)pa)[idx] = pack4(x.x, x.y, x.z, x.w);
        return;
    }

    const int tile = blockIdx.x - PACKA_BLOCKS;
    const int t  = threadIdx.x;
    const int n0 = (tile & 63) * 64;
    const int k0 = (tile >> 6) * 64;

    // Load 64x64 int32 tile, coalesced int4 loads.
#pragma unroll
    for (int i = 0; i < 4; ++i) {
        int v   = t + 256 * i;         // 0..1023 int4-groups
        int row = v >> 4;              // k within tile
        int cq  = v & 15;              // int4 group within row
        int4 x = *(const int4*)(w + (size_t)(k0 + row) * N_DIM + n0 + cq * 4);
        lds[row][cq * 4 + 0] = x.x;
        lds[row][cq * 4 + 1] = x.y;
        lds[row][cq * 4 + 2] = x.z;
        lds[row][cq * 4 + 3] = x.w;
    }
    __syncthreads();

    // Thread t emits 16 bytes of output row n_local: wt[n0+n_local][k0+c*16 ..]
    const int n_local = t >> 2;        // 0..63
    const int c       = t & 3;         // 16-byte k-chunk
    uint32_t o[4];
#pragma unroll
    for (int j = 0; j < 4; ++j)
        o[j] = pack4(lds[c * 16 + j * 4 + 0][n_local],
                     lds[c * 16 + j * 4 + 1][n_local],
                     lds[c * 16 + j * 4 + 2][n_local],
                     lds[c * 16 + j * 4 + 3][n_local]);
    *(uint4*)(wt + (size_t)(n0 + n_local) * K_DIM + k0 + c * 16) =
        make_uint4(o[0], o[1], o[2], o[3]);
}

// ---------------------------------------------------------------------------
// int8 GEMM. Block tile 128(M) x 128(N), BK = 128 bytes. 256 threads =
// 4 waves in 2x2; each wave computes 64x64 via 2x2 grid of
// mfma_i32_32x32x32_i8 (4404 TOPS ubench vs 3944 for 16x16x64: +12% rate,
// half the MFMA issue slots).
// LDS: sA[128 rows][128 k-bytes], sB[128 n-rows][128 k-bytes], both with the
// 16B-chunk XOR swizzle (chunk ^= row&7) applied at *global-address* time so
// the global_load_lds contiguous-dest constraint is preserved.
// ---------------------------------------------------------------------------
__device__ __forceinline__ void async_copy16(const void* gptr, void* lptr)
{
    __builtin_amdgcn_global_load_lds(
        (const __attribute__((address_space(1))) uint32_t*)gptr,
        (__attribute__((address_space(3))) uint32_t*)lptr,
        16, 0, 0);
}

__global__ void __launch_bounds__(256) int8_gemm_kernel(
    const uint8_t* __restrict__ A,    // [M][K] int8 bytes (packed)
    const uint8_t* __restrict__ Wt,   // [N][K] int8 bytes (pre-transposed)
    const float*   __restrict__ a_s,  // [M]
    const float*   __restrict__ w_s,  // [N]
    float*         __restrict__ out)  // [M][N] f32 (fp16-rounded)
{
    __shared__ __align__(16) uint8_t sA[128 * 128];
    __shared__ __align__(16) uint8_t sB[128 * 128];

    const int tid   = threadIdx.x;
    const int wave  = tid >> 6;
    const int lane  = tid & 63;
    const int waveM = wave >> 1;      // 0..1
    const int waveN = wave & 1;       // 0..1

    const int bm = blockIdx.x & 63;   // 64 m-blocks (fast)
    const int bn = blockIdx.x >> 6;   // 32 n-blocks
    const int m0 = bm * 128;
    const int n0 = bn * 128;

    v16i acc[2][2];
#pragma unroll
    for (int i = 0; i < 2; ++i)
#pragma unroll
        for (int j = 0; j < 2; ++j)
#pragma unroll
            for (int r = 0; r < 16; ++r)
                acc[i][j][r] = 0;

    // Staging geometry: 16 regions of 1KB each (8 rows x 128B). Region
    // = wave*4 + s. Lane covers row (lane>>3) of the region, 16B chunk (lane&7).
    const int sr = lane >> 3;   // row within region
    const int sc = lane & 7;    // chunk within row

    // Fragment geometry for 32x32x32 i8:
    //   A: lane holds A[m = lane&31][k = (lane>>5)*16 .. +15]
    //   B: lane holds B[k = (lane>>5)*16 .. +15][n = lane&31]  (Wt row-major)
    const int frow = lane & 31;     // row within 32-tile
    const int fk   = lane >> 5;     // which 16B k-half

    for (int kt = 0; kt < K_DIM / 128; ++kt) {
        const int k0 = kt * 128;
#pragma unroll
        for (int s = 0; s < 4; ++s) {
            const int region = wave * 4 + s;        // wave-uniform
            const int r      = region * 8 + sr;     // tile row 0..127
            const int g      = sc ^ (r & 7);        // swizzled global chunk
            async_copy16(A  + (size_t)(m0 + r) * K_DIM + k0 + g * 16,
                         &sA[region * 1024]);
            async_copy16(Wt + (size_t)(n0 + r) * K_DIM + k0 + g * 16,
                         &sB[region * 1024]);
        }
        __syncthreads();   // drains vmcnt(0): staged data visible

#pragma unroll
        for (int s = 0; s < 4; ++s) {              // K-step of 32 bytes
            const int gc = s * 2 + fk;             // global 16B k-chunk
            v4i af[2], bf[2];
#pragma unroll
            for (int t = 0; t < 2; ++t) {
                const int mr = waveM * 64 + t * 32 + frow;
                af[t] = *(const v4i*)(sA + mr * 128 + ((gc ^ (mr & 7)) << 4));
                const int nr = waveN * 64 + t * 32 + frow;
                bf[t] = *(const v4i*)(sB + nr * 128 + ((gc ^ (nr & 7)) << 4));
            }
#pragma unroll
            for (int mt = 0; mt < 2; ++mt)
#pragma unroll
                for (int nt = 0; nt < 2; ++nt)
                    acc[mt][nt] = __builtin_amdgcn_mfma_i32_32x32x32_i8(
                        af[mt], bf[nt], acc[mt][nt], 0, 0, 0);
        }
        __syncthreads();   // compute done before next overwrite
    }

    // Epilogue. 32x32 C/D layout: col = lane&31,
    // row = (reg&3) + 8*(reg>>2) + 4*(lane>>5).
    const int col   = lane & 31;
    const int rbase = (lane >> 5) * 4;

#pragma unroll
    for (int mt = 0; mt < 2; ++mt) {
        const int mrow0 = m0 + waveM * 64 + mt * 32 + rbase;
        float asv[16];
#pragma unroll
        for (int reg = 0; reg < 16; ++reg)
            asv[reg] = a_s[mrow0 + (reg & 3) + 8 * (reg >> 2)];
#pragma unroll
        for (int nt = 0; nt < 2; ++nt) {
            const int n = n0 + waveN * 64 + nt * 32 + col;
            const float wsv = w_s[n];
#pragma unroll
            for (int reg = 0; reg < 16; ++reg) {
                const int row = mrow0 + (reg & 3) + 8 * (reg >> 2);
                float v = (float)acc[mt][nt][reg] * asv[reg] * wsv;
                v = (float)(_Float16)v;   // match reference's fp16 cast
                out[(size_t)row * N_DIM + n] = v;
            }
        }
    }
}

// ---------------------------------------------------------------------------
extern "C" void kernel_launch(void* const* d_in, const int* in_sizes, int n_in,
                              void* d_out, int out_size, void* d_ws, size_t ws_size,
                              hipStream_t stream)
{
    const int*   a   = (const int*)  d_in[0];  // int32-widened int8 [8192][4096]
    const float* a_s = (const float*)d_in[1];  // [8192]
    const int*   w   = (const int*)  d_in[2];  // int32-widened int8 [4096][4096]
    const float* w_s = (const float*)d_in[3];  // [4096]
    float*       out = (float*)d_out;

    uint8_t* wt = (uint8_t*)d_ws;                          // 16 MiB
    uint8_t* pa = (uint8_t*)d_ws + (size_t)N_DIM * K_DIM;  // 32 MiB

    prepare_kernel<<<PACKA_BLOCKS + TRANS_BLOCKS, 256, 0, stream>>>(a, w, pa, wt);

    int8_gemm_kernel<<<(M_DIM / 128) * (N_DIM / 128), 256, 0, stream>>>(
        pa, wt, a_s, w_s, out);
}